// Round 1
// baseline (340.480 us; speedup 1.0000x reference)
//
#include <hip/hip_runtime.h>
#include <hip/hip_bf16.h>
#include <math.h>

// AFM forward: out[b] = linear(b) + softmax-weighted pair-interaction projection.
// B=4096, F=26 fields, d=64 embed dim, P=325 pairs, af=64 attention dim.

#define NF 26
#define NP 325          // 26*25/2
#define ED 64           // embed dim
#define AF 64           // attention hidden dim
#define NDENSE 13
#define BLOCK 384       // 6 waves; 325 pairs -> one pair per lane (59 idle lanes in wave 5)

__global__ void transpose_w1(const float* __restrict__ W1, float* __restrict__ W1t) {
    int idx = blockIdx.x * blockDim.x + threadIdx.x;   // 0..4095
    int d = idx >> 6, a = idx & 63;
    W1t[a * ED + d] = W1[d * AF + a];
}

__global__ __launch_bounds__(BLOCK)
void afm_kernel(const int*   __restrict__ sparse,   // [B,26]
                const float* __restrict__ dense,    // [B,13]
                const float* __restrict__ etab,     // [V,64]
                const float* __restrict__ ltab,     // [V]
                const float* __restrict__ wdense,   // [13]
                const float* __restrict__ bias,     // [1]
                const float* __restrict__ b1,       // [64]
                const float* __restrict__ w2,       // [64]
                const float* __restrict__ proj,     // [64]
                const float* __restrict__ w1t,      // [64,64]  W1 transposed (a-major)
                float*       __restrict__ out)      // [B]
{
    const int b    = blockIdx.x;
    const int t    = threadIdx.x;
    const int wave = t >> 6;
    const int lane = t & 63;

    __shared__ float emb_s[NF][68];          // stride 68: 16B-aligned rows, staggered banks
    __shared__ float scores_s[NP];
    __shared__ unsigned char pi_s[NP], pj_s[NP];
    __shared__ float wred[6];
    __shared__ float gbcast;
    __shared__ float lin_sum;
    __shared__ float partial[6][ED];

    // ---- pair index tables (i<j, row-major triu order as np.triu_indices) ----
    if (t < NP) {
        int rem = t, i = 0;
        while (rem >= NF - 1 - i) { rem -= NF - 1 - i; ++i; }
        pi_s[t] = (unsigned char)i;
        pj_s[t] = (unsigned char)(i + 1 + rem);
    }

    // ---- stage embeddings: 26 rows x 16 float4 quads ----
    for (int task = t; task < NF * 16; task += BLOCK) {
        int f = task >> 4, q = task & 15;
        int row = sparse[b * NF + f];
        float4 v = *(const float4*)(etab + (size_t)row * ED + 4 * q);
        *(float4*)(&emb_s[f][4 * q]) = v;
    }

    // ---- linear part (wave 0): sum lin_table gather + dense dot + bias ----
    if (wave == 0) {
        float v = 0.f;
        if (lane < NF) {
            v = ltab[sparse[b * NF + lane]];
        } else if (lane >= 32 && lane < 32 + NDENSE) {
            int k = lane - 32;
            v = dense[b * NDENSE + k] * wdense[k];
        }
        #pragma unroll
        for (int off = 32; off >= 1; off >>= 1) v += __shfl_xor(v, off, 64);
        if (lane == 0) lin_sum = v + bias[0];
    }

    __syncthreads();

    // ---- phase 1: per-pair attention MLP. lane = pair. ----
    float logit = -INFINITY;
    if (t < NP) {
        const int i = pi_s[t], j = pj_s[t];
        float4 xq[16];                        // att_x for this pair, in registers
        #pragma unroll
        for (int q = 0; q < 16; ++q) {
            float4 a4 = *(const float4*)(&emb_s[i][4 * q]);
            float4 b4 = *(const float4*)(&emb_s[j][4 * q]);
            xq[q].x = a4.x * b4.x; xq[q].y = a4.y * b4.y;
            xq[q].z = a4.z * b4.z; xq[q].w = a4.w * b4.w;
        }
        float lg = 0.f;
        for (int a = 0; a < AF; ++a) {        // W1t rows via uniform (scalar) loads
            const float4* wr = (const float4*)(w1t + a * ED);
            float acc = b1[a];
            #pragma unroll
            for (int q = 0; q < 16; ++q) {
                float4 w = wr[q];
                acc = fmaf(xq[q].x, w.x, acc);
                acc = fmaf(xq[q].y, w.y, acc);
                acc = fmaf(xq[q].z, w.z, acc);
                acc = fmaf(xq[q].w, w.w, acc);
            }
            lg = fmaf(fmaxf(acc, 0.f), w2[a], lg);
        }
        logit = lg;
    }

    // ---- softmax over 325 logits ----
    float m = logit;
    #pragma unroll
    for (int off = 32; off >= 1; off >>= 1) m = fmaxf(m, __shfl_xor(m, off, 64));
    if (lane == 0) wred[wave] = m;
    __syncthreads();
    if (t == 0) {
        float mm = wred[0];
        #pragma unroll
        for (int w = 1; w < 6; ++w) mm = fmaxf(mm, wred[w]);
        gbcast = mm;
    }
    __syncthreads();
    const float gmax = gbcast;
    float e = (t < NP) ? __expf(logit - gmax) : 0.f;
    float s = e;
    #pragma unroll
    for (int off = 32; off >= 1; off >>= 1) s += __shfl_xor(s, off, 64);
    if (lane == 0) wred[wave] = s;
    __syncthreads();
    if (t == 0) {
        float ss = 0.f;
        #pragma unroll
        for (int w = 0; w < 6; ++w) ss += wred[w];
        gbcast = 1.0f / ss;
    }
    __syncthreads();
    if (t < NP) scores_s[t] = e * gbcast;
    __syncthreads();

    // ---- phase 3: att_out[d] = sum_p score_p * emb_i[d] * emb_j[d] ----
    // lane -> (d-quad q, pair-sub): wave covers 4 pairs per iteration.
    {
        const int q   = lane & 15;
        const int sub = lane >> 4;
        float4 acc4 = make_float4(0.f, 0.f, 0.f, 0.f);
        #pragma unroll
        for (int iter = 0; iter < 14; ++iter) {   // 24 pairs/iter * 14 = 336 >= 325
            int p = 24 * iter + wave * 4 + sub;
            if (p < NP) {
                float sc = scores_s[p];
                int i = pi_s[p], j = pj_s[p];
                float4 ei = *(const float4*)(&emb_s[i][4 * q]);
                float4 ej = *(const float4*)(&emb_s[j][4 * q]);
                acc4.x = fmaf(sc, ei.x * ej.x, acc4.x);
                acc4.y = fmaf(sc, ei.y * ej.y, acc4.y);
                acc4.z = fmaf(sc, ei.z * ej.z, acc4.z);
                acc4.w = fmaf(sc, ei.w * ej.w, acc4.w);
            }
        }
        // reduce across the 4 sub-groups (lanes l, l+16, l+32, l+48)
        #pragma unroll
        for (int off = 16; off <= 32; off <<= 1) {
            acc4.x += __shfl_xor(acc4.x, off, 64);
            acc4.y += __shfl_xor(acc4.y, off, 64);
            acc4.z += __shfl_xor(acc4.z, off, 64);
            acc4.w += __shfl_xor(acc4.w, off, 64);
        }
        if (sub == 0) *(float4*)(&partial[wave][4 * q]) = acc4;
    }
    __syncthreads();

    // ---- final: combine wave partials, project with p, add linear ----
    if (wave == 0 && lane < 16) {
        float4 s4 = make_float4(0.f, 0.f, 0.f, 0.f);
        #pragma unroll
        for (int w = 0; w < 6; ++w) {
            float4 v = *(const float4*)(&partial[w][4 * lane]);
            s4.x += v.x; s4.y += v.y; s4.z += v.z; s4.w += v.w;
        }
        float4 p4 = *(const float4*)(proj + 4 * lane);
        float r = s4.x * p4.x + s4.y * p4.y + s4.z * p4.z + s4.w * p4.w;
        #pragma unroll
        for (int off = 8; off >= 1; off >>= 1) r += __shfl_xor(r, off, 64);
        if (lane == 0) out[b] = lin_sum + r;
    }
}

extern "C" void kernel_launch(void* const* d_in, const int* in_sizes, int n_in,
                              void* d_out, int out_size, void* d_ws, size_t ws_size,
                              hipStream_t stream) {
    const int*   sparse = (const int*)  d_in[0];   // [B,26] int32
    const float* dense  = (const float*)d_in[1];   // [B,13]
    const float* etab   = (const float*)d_in[2];   // [100000,64]
    const float* ltab   = (const float*)d_in[3];   // [100000]
    const float* wdense = (const float*)d_in[4];   // [13]
    const float* bias   = (const float*)d_in[5];   // [1]
    const float* W1     = (const float*)d_in[6];   // [64,64]
    const float* b1     = (const float*)d_in[7];   // [64]
    const float* w2     = (const float*)d_in[8];   // [64]
    const float* proj   = (const float*)d_in[9];   // [64]
    float* outp = (float*)d_out;                   // [B]
    float* w1t  = (float*)d_ws;                    // 64*64 fp32 scratch

    const int B = in_sizes[0] / NF;

    transpose_w1<<<dim3(16), dim3(256), 0, stream>>>(W1, w1t);
    afm_kernel<<<dim3(B), dim3(BLOCK), 0, stream>>>(
        sparse, dense, etab, ltab, wdense, bias, b1, w2, proj, w1t, outp);
    (void)n_in; (void)out_size; (void)ws_size;
}

// Round 2
// 166.484 us; speedup vs baseline: 2.0451x; 2.0451x over previous
//
#include <hip/hip_runtime.h>
#include <hip/hip_bf16.h>
#include <math.h>

// AFM forward: out[b] = linear(b) + softmax-weighted pair-interaction projection.
// B=4096, F=26 fields, d=64 embed dim, P=325 pairs, af=64 attention dim.
//
// R2: pair-MLP via bf16 MFMA 16x16x32. A-fragments built in registers from
// emb_s (no att_x materialization); B-fragments (W1^T bf16) preloaded once
// per wave. R1 post-mortem: VGPR=44 showed the compiler re-read emb_s every
// a-iteration -> LDS-BW bound (~360 us floor). MFMA removes that loop entirely.

#define NF 26
#define NP 325          // 26*25/2
#define NPP 336         // padded to 21 m-tiles of 16
#define NMT 21
#define ED 64           // embed dim
#define AF 64           // attention hidden dim
#define NDENSE 13
#define BLOCK 384       // 6 waves

typedef __attribute__((ext_vector_type(8))) short short8;   // 8 bf16 (4 VGPRs)
typedef __attribute__((ext_vector_type(4))) float f32x4;

__device__ __forceinline__ short f2bf(float x) {
    union { float f; unsigned u; } c; c.f = x;
    unsigned r = c.u + 0x7fff + ((c.u >> 16) & 1);   // RNE
    return (short)(r >> 16);
}

__global__ __launch_bounds__(BLOCK)
void afm_kernel(const int*   __restrict__ sparse,   // [B,26]
                const float* __restrict__ dense,    // [B,13]
                const float* __restrict__ etab,     // [V,64]
                const float* __restrict__ ltab,     // [V]
                const float* __restrict__ wdense,   // [13]
                const float* __restrict__ bias,     // [1]
                const float* __restrict__ W1,       // [64,64] (d-major: W1[d][a])
                const float* __restrict__ b1,       // [64]
                const float* __restrict__ w2,       // [64]
                const float* __restrict__ proj,     // [64]
                float*       __restrict__ out)      // [B]
{
    const int b    = blockIdx.x;
    const int t    = threadIdx.x;
    const int wave = t >> 6;
    const int lane = t & 63;
    const int qd   = lane >> 4;     // quad 0..3
    const int ln   = lane & 15;

    __shared__ alignas(16) float emb_s[NF][68];      // stride 68 fl = 272 B (16B-aligned rows)
    __shared__ alignas(16) short w1t_s[AF][72];      // [a][d] bf16, stride 144 B
    __shared__ alignas(16) float scores_s[NPP];
    __shared__ unsigned char pi_s[NPP], pj_s[NPP];
    __shared__ float wred[6];
    __shared__ float gbcast;
    __shared__ float lin_sum;
    __shared__ alignas(16) float partial[6][ED];

    // ---- pair index tables (np.triu_indices order), padded rows -> (0,0) ----
    if (t < NPP) {
        if (t < NP) {
            int rem = t, i = 0;
            while (rem >= NF - 1 - i) { rem -= NF - 1 - i; ++i; }
            pi_s[t] = (unsigned char)i;
            pj_s[t] = (unsigned char)(i + 1 + rem);
        } else {
            pi_s[t] = 0; pj_s[t] = 0;
        }
    }

    // ---- stage embeddings: 26 rows x 16 float4 quads ----
    for (int task = t; task < NF * 16; task += BLOCK) {
        int f = task >> 4, q = task & 15;
        int row = sparse[b * NF + f];
        float4 v = *(const float4*)(etab + (size_t)row * ED + 4 * q);
        *(float4*)(&emb_s[f][4 * q]) = v;
    }

    // ---- convert W1 -> W1^T bf16 in LDS: w1t_s[a][d] ----
    for (int idx = t; idx < ED * AF; idx += BLOCK) {
        int dd = idx >> 6, a = idx & 63;          // W1 is [d][a], idx coalesced
        w1t_s[a][dd] = f2bf(W1[idx]);
    }

    // ---- linear part (wave 0) ----
    if (wave == 0) {
        float v = 0.f;
        if (lane < NF) {
            v = ltab[sparse[b * NF + lane]];
        } else if (lane >= 32 && lane < 32 + NDENSE) {
            int k = lane - 32;
            v = dense[b * NDENSE + k] * wdense[k];
        }
        #pragma unroll
        for (int off = 32; off >= 1; off >>= 1) v += __shfl_xor(v, off, 64);
        if (lane == 0) lin_sum = v + bias[0];
    }

    __syncthreads();

    // ---- B-fragment preload: bf[nt][kh] = W1[k][n], k=kh*32+qd*8+j, n=nt*16+ln ----
    short8 bfr[4][2];
    #pragma unroll
    for (int nt = 0; nt < 4; ++nt)
        #pragma unroll
        for (int kh = 0; kh < 2; ++kh)
            bfr[nt][kh] = *(const short8*)(&w1t_s[nt * 16 + ln][kh * 32 + qd * 8]);

    float b1v[4], w2v[4];
    #pragma unroll
    for (int nt = 0; nt < 4; ++nt) {
        b1v[nt] = b1[nt * 16 + ln];
        w2v[nt] = w2[nt * 16 + ln];
    }

    // ---- phase 1: pair-MLP logits via MFMA; wave owns m-tiles mt, mt+6, ... ----
    for (int mt = wave; mt < NMT; mt += 6) {
        const int p = mt * 16 + ln;               // A-row this lane supplies
        const int fi = pi_s[p], fj = pj_s[p];

        short8 afr[2];                            // A-frags for kh=0,1
        #pragma unroll
        for (int kh = 0; kh < 2; ++kh) {
            const int d0 = kh * 32 + qd * 8;      // k = d0 + j
            float4 ia = *(const float4*)(&emb_s[fi][d0]);
            float4 ib = *(const float4*)(&emb_s[fi][d0 + 4]);
            float4 ja = *(const float4*)(&emb_s[fj][d0]);
            float4 jb = *(const float4*)(&emb_s[fj][d0 + 4]);
            short8 a;
            a[0] = f2bf(ia.x * ja.x); a[1] = f2bf(ia.y * ja.y);
            a[2] = f2bf(ia.z * ja.z); a[3] = f2bf(ia.w * ja.w);
            a[4] = f2bf(ib.x * jb.x); a[5] = f2bf(ib.y * jb.y);
            a[6] = f2bf(ib.z * jb.z); a[7] = f2bf(ib.w * jb.w);
            afr[kh] = a;
        }

        float lg0 = 0.f, lg1 = 0.f, lg2 = 0.f, lg3 = 0.f;
        #pragma unroll
        for (int nt = 0; nt < 4; ++nt) {
            f32x4 acc = {0.f, 0.f, 0.f, 0.f};
            acc = __builtin_amdgcn_mfma_f32_16x16x32_bf16(afr[0], bfr[nt][0], acc, 0, 0, 0);
            acc = __builtin_amdgcn_mfma_f32_16x16x32_bf16(afr[1], bfr[nt][1], acc, 0, 0, 0);
            // C layout: col = ln (a within tile), row = qd*4 + reg (pair)
            lg0 = fmaf(fmaxf(acc[0] + b1v[nt], 0.f), w2v[nt], lg0);
            lg1 = fmaf(fmaxf(acc[1] + b1v[nt], 0.f), w2v[nt], lg1);
            lg2 = fmaf(fmaxf(acc[2] + b1v[nt], 0.f), w2v[nt], lg2);
            lg3 = fmaf(fmaxf(acc[3] + b1v[nt], 0.f), w2v[nt], lg3);
        }
        // reduce over the 16 cols (ln); offsets <16 stay within the 16-lane group
        #pragma unroll
        for (int off = 1; off <= 8; off <<= 1) {
            lg0 += __shfl_xor(lg0, off, 64);
            lg1 += __shfl_xor(lg1, off, 64);
            lg2 += __shfl_xor(lg2, off, 64);
            lg3 += __shfl_xor(lg3, off, 64);
        }
        if (ln == 0)
            *(float4*)(&scores_s[mt * 16 + qd * 4]) = make_float4(lg0, lg1, lg2, lg3);
    }

    __syncthreads();

    // ---- softmax over 325 logits ----
    float logit = (t < NP) ? scores_s[t] : -INFINITY;
    float m = logit;
    #pragma unroll
    for (int off = 32; off >= 1; off >>= 1) m = fmaxf(m, __shfl_xor(m, off, 64));
    if (lane == 0) wred[wave] = m;
    __syncthreads();
    if (t == 0) {
        float mm = wred[0];
        #pragma unroll
        for (int w = 1; w < 6; ++w) mm = fmaxf(mm, wred[w]);
        gbcast = mm;
    }
    __syncthreads();
    const float gmax = gbcast;
    float e = (t < NP) ? __expf(logit - gmax) : 0.f;
    float s = e;
    #pragma unroll
    for (int off = 32; off >= 1; off >>= 1) s += __shfl_xor(s, off, 64);
    if (lane == 0) wred[wave] = s;
    __syncthreads();
    if (t == 0) {
        float ss = 0.f;
        #pragma unroll
        for (int w = 0; w < 6; ++w) ss += wred[w];
        gbcast = 1.0f / ss;
    }
    __syncthreads();
    if (t < NP) scores_s[t] = e * gbcast;
    __syncthreads();

    // ---- phase 3: att_out[d] = sum_p score_p * emb_i[d] * emb_j[d] (fp32) ----
    {
        const int q   = lane & 15;
        const int sub = lane >> 4;
        float4 acc4 = make_float4(0.f, 0.f, 0.f, 0.f);
        #pragma unroll
        for (int iter = 0; iter < 14; ++iter) {   // 24 pairs/iter * 14 = 336 >= 325
            int p = 24 * iter + wave * 4 + sub;
            if (p < NP) {
                float sc = scores_s[p];
                int i = pi_s[p], j = pj_s[p];
                float4 ei = *(const float4*)(&emb_s[i][4 * q]);
                float4 ej = *(const float4*)(&emb_s[j][4 * q]);
                acc4.x = fmaf(sc, ei.x * ej.x, acc4.x);
                acc4.y = fmaf(sc, ei.y * ej.y, acc4.y);
                acc4.z = fmaf(sc, ei.z * ej.z, acc4.z);
                acc4.w = fmaf(sc, ei.w * ej.w, acc4.w);
            }
        }
        #pragma unroll
        for (int off = 16; off <= 32; off <<= 1) {
            acc4.x += __shfl_xor(acc4.x, off, 64);
            acc4.y += __shfl_xor(acc4.y, off, 64);
            acc4.z += __shfl_xor(acc4.z, off, 64);
            acc4.w += __shfl_xor(acc4.w, off, 64);
        }
        if (sub == 0) *(float4*)(&partial[wave][4 * q]) = acc4;
    }
    __syncthreads();

    // ---- final: combine wave partials, project with p, add linear ----
    if (wave == 0 && lane < 16) {
        float4 s4 = make_float4(0.f, 0.f, 0.f, 0.f);
        #pragma unroll
        for (int w = 0; w < 6; ++w) {
            float4 v = *(const float4*)(&partial[w][4 * lane]);
            s4.x += v.x; s4.y += v.y; s4.z += v.z; s4.w += v.w;
        }
        float4 p4 = *(const float4*)(proj + 4 * lane);
        float r = s4.x * p4.x + s4.y * p4.y + s4.z * p4.z + s4.w * p4.w;
        #pragma unroll
        for (int off = 8; off >= 1; off >>= 1) r += __shfl_xor(r, off, 64);
        if (lane == 0) out[b] = lin_sum + r;
    }
}

extern "C" void kernel_launch(void* const* d_in, const int* in_sizes, int n_in,
                              void* d_out, int out_size, void* d_ws, size_t ws_size,
                              hipStream_t stream) {
    const int*   sparse = (const int*)  d_in[0];   // [B,26] int32
    const float* dense  = (const float*)d_in[1];   // [B,13]
    const float* etab   = (const float*)d_in[2];   // [100000,64]
    const float* ltab   = (const float*)d_in[3];   // [100000]
    const float* wdense = (const float*)d_in[4];   // [13]
    const float* bias   = (const float*)d_in[5];   // [1]
    const float* W1     = (const float*)d_in[6];   // [64,64]
    const float* b1     = (const float*)d_in[7];   // [64]
    const float* w2     = (const float*)d_in[8];   // [64]
    const float* proj   = (const float*)d_in[9];   // [64]
    float* outp = (float*)d_out;                   // [B]

    const int B = in_sizes[0] / NF;

    afm_kernel<<<dim3(B), dim3(BLOCK), 0, stream>>>(
        sparse, dense, etab, ltab, wdense, bias, W1, b1, w2, proj, outp);
    (void)n_in; (void)out_size; (void)ws_size; (void)d_ws;
}

// Round 3
// 129.475 us; speedup vs baseline: 2.6297x; 1.2858x over previous
//
#include <hip/hip_runtime.h>
#include <math.h>

// AFM forward: out[b] = linear(b) + softmax-weighted pair-interaction projection.
// B=4096, F=26, d=64, P=325 pairs, af=64.
//
// R3: one WAVE per batch row, 4 waves/block, zero __syncthreads (wave-local
// fence+wave_barrier only -> no cross-wave barrier drain). W1^T f16 + pair
// table hoisted to a prep kernel in d_ws (R2 post-mortem: per-block W1->LDS
// conversion was 8-way bank-conflicted and redundant; conflicts 5.3M).
// Whole pipeline f16: emb staged f16 in LDS (stride 72: 16B-aligned rows,
// 8 bank-groups), MFMA f16 16x16x32, phase-3 packed v_pk_fma_f16.

#define NF 26
#define NP 325
#define NPP 336          // padded to 21 m-tiles of 16
#define NMT 21
#define ED 64
#define AF 64
#define NDENSE 13
#define WPB 4            // waves (rows) per block
#define BLOCK (WPB * 64)
#define ESTRIDE 72       // f16 elems per emb row: 144 B (16B-aligned, 36 dwords -> 8 bank groups)

typedef __attribute__((ext_vector_type(8))) _Float16 half8;
typedef __attribute__((ext_vector_type(4))) _Float16 half4;
typedef __attribute__((ext_vector_type(4))) float f32x4;

__device__ __forceinline__ void wsync() {
    // wave-local producer->consumer ordering through LDS: drain counters +
    // compiler/scheduler barrier. All lanes of a wave are lockstep; no
    // cross-wave LDS sharing exists in this kernel.
    __builtin_amdgcn_fence(__ATOMIC_ACQ_REL, "workgroup");
    __builtin_amdgcn_wave_barrier();
}

__global__ void prep_kernel(const float* __restrict__ W1,
                            _Float16* __restrict__ w1t,        // [64][64] = W1^T, f16
                            unsigned short* __restrict__ tab)  // [336] i | j<<8
{
    int t = threadIdx.x;
    for (int idx = t; idx < ED * AF; idx += 256) {
        int d = idx >> 6, a = idx & 63;       // W1 is [d][a]
        w1t[a * ED + d] = (_Float16)W1[idx];
    }
    if (t < NPP) {
        unsigned short v = 0;
        if (t < NP) {
            int rem = t, i = 0;
            while (rem >= NF - 1 - i) { rem -= NF - 1 - i; ++i; }
            v = (unsigned short)(i | ((i + 1 + rem) << 8));
        }
        tab[t] = v;
    }
}

__global__ __launch_bounds__(BLOCK, 4)
void afm_kernel(const int*   __restrict__ sparse,   // [B,26]
                const float* __restrict__ dense,    // [B,13]
                const float* __restrict__ etab,     // [V,64]
                const float* __restrict__ ltab,     // [V]
                const float* __restrict__ wdense,   // [13]
                const float* __restrict__ bias,     // [1]
                const float* __restrict__ b1,       // [64]
                const float* __restrict__ w2,       // [64]
                const float* __restrict__ proj,     // [64]
                const _Float16* __restrict__ w1t,   // [64][64] f16 (a-major)
                const unsigned short* __restrict__ tab, // [336]
                float*       __restrict__ out,      // [B]
                int B)
{
    const int t    = threadIdx.x;
    const int wave = t >> 6;
    const int lane = t & 63;
    const int qd   = lane >> 4;     // quad 0..3
    const int ln   = lane & 15;

    const int r = blockIdx.x * WPB + wave;   // this wave's batch row
    if (r >= B) return;                      // safe: no block-level barriers

    __shared__ alignas(16) _Float16 emb_all[WPB][NF][ESTRIDE];  // 14976 B
    __shared__ alignas(16) float    sc_all[WPB][NPP];           //  5376 B

    _Float16 (* __restrict__ emb)[ESTRIDE] = emb_all[wave];
    float* __restrict__ scores = sc_all[wave];

    // ---- B-fragment preload from global (L2-hot 8 KB): bfr[nt][kh] ----
    // B[k][n]: n = nt*16+ln, k = kh*32 + qd*8 + j  -> w1t[n][k]
    half8 bfr[4][2];
    #pragma unroll
    for (int nt = 0; nt < 4; ++nt)
        #pragma unroll
        for (int kh = 0; kh < 2; ++kh)
            bfr[nt][kh] = *(const half8*)(w1t + (nt * 16 + ln) * ED + kh * 32 + qd * 8);

    float b1v[4], w2v[4];
    #pragma unroll
    for (int nt = 0; nt < 4; ++nt) {
        b1v[nt] = b1[nt * 16 + ln];
        w2v[nt] = w2[nt * 16 + ln];
    }

    // ---- stage this row's 26 embeddings into LDS as f16 ----
    const int* __restrict__ srow = sparse + r * NF;
    for (int task = lane; task < NF * 16; task += 64) {
        int f = task >> 4, q = task & 15;
        float4 v = *(const float4*)(etab + (size_t)srow[f] * ED + q * 4);
        half4 h = { (_Float16)v.x, (_Float16)v.y, (_Float16)v.z, (_Float16)v.w };
        *(half4*)(&emb[f][q * 4]) = h;
    }

    // ---- linear part (register-only, wave-local) ----
    float lin = 0.f;
    if (lane < NF) {
        lin = ltab[srow[lane]];
    } else if (lane >= 32 && lane < 32 + NDENSE) {
        int k = lane - 32;
        lin = dense[r * NDENSE + k] * wdense[k];
    }
    #pragma unroll
    for (int off = 32; off >= 1; off >>= 1) lin += __shfl_xor(lin, off, 64);
    lin += bias[0];

    wsync();   // emb visible to all lanes

    // ---- phase 1: pair-MLP logits via MFMA f16; this wave does all 21 tiles ----
    for (int mt = 0; mt < NMT; ++mt) {
        const int p0 = mt * 16 + ln;
        const unsigned pp = tab[p0];
        const int fi = pp & 0xff, fj = pp >> 8;

        // A[m=ln][k=qd*8+j] = emb[fi][k] * emb[fj][k], two K-halves
        half8 a0 = *(const half8*)(&emb[fi][qd * 8])      * *(const half8*)(&emb[fj][qd * 8]);
        half8 a1 = *(const half8*)(&emb[fi][32 + qd * 8]) * *(const half8*)(&emb[fj][32 + qd * 8]);

        float lg[4] = {0.f, 0.f, 0.f, 0.f};
        #pragma unroll
        for (int nt = 0; nt < 4; ++nt) {
            f32x4 acc = {0.f, 0.f, 0.f, 0.f};
            acc = __builtin_amdgcn_mfma_f32_16x16x32_f16(a0, bfr[nt][0], acc, 0, 0, 0);
            acc = __builtin_amdgcn_mfma_f32_16x16x32_f16(a1, bfr[nt][1], acc, 0, 0, 0);
            // C layout: col = ln (a), row = qd*4 + reg (pair)
            #pragma unroll
            for (int rr = 0; rr < 4; ++rr)
                lg[rr] = fmaf(fmaxf(acc[rr] + b1v[nt], 0.f), w2v[nt], lg[rr]);
        }
        #pragma unroll
        for (int off = 1; off <= 8; off <<= 1) {
            #pragma unroll
            for (int rr = 0; rr < 4; ++rr) lg[rr] += __shfl_xor(lg[rr], off, 64);
        }
        if (ln == 0) {
            const int pr = mt * 16 + qd * 4;
            float4 st;
            st.x = (pr + 0 < NP) ? lg[0] : -INFINITY;
            st.y = (pr + 1 < NP) ? lg[1] : -INFINITY;
            st.z = (pr + 2 < NP) ? lg[2] : -INFINITY;
            st.w = (pr + 3 < NP) ? lg[3] : -INFINITY;
            *(float4*)(&scores[pr]) = st;
        }
    }

    wsync();   // logits visible

    // ---- softmax over 336 (pads are -inf) , wave-local ----
    float v[6];
    #pragma unroll
    for (int k = 0; k < 6; ++k) {
        int p = lane + (k << 6);
        v[k] = (p < NPP) ? scores[p] : -INFINITY;
    }
    float m = v[0];
    #pragma unroll
    for (int k = 1; k < 6; ++k) m = fmaxf(m, v[k]);
    #pragma unroll
    for (int off = 32; off >= 1; off >>= 1) m = fmaxf(m, __shfl_xor(m, off, 64));
    float e[6], esum = 0.f;
    #pragma unroll
    for (int k = 0; k < 6; ++k) { e[k] = __expf(v[k] - m); esum += e[k]; }
    #pragma unroll
    for (int off = 32; off >= 1; off >>= 1) esum += __shfl_xor(esum, off, 64);
    const float rinv = 1.0f / esum;
    #pragma unroll
    for (int k = 0; k < 6; ++k) {
        int p = lane + (k << 6);
        if (p < NPP) scores[p] = e[k] * rinv;
    }

    wsync();   // normalized scores visible

    // ---- phase 3: att_out[d] = sum_p s_p * emb_i[d]*emb_j[d], packed f16 ----
    const int dg  = lane & 7;        // dim group: d = dg*8 .. dg*8+7
    const int sub = lane >> 3;       // pair sub 0..7
    half8 acc8 = { (_Float16)0.f, (_Float16)0.f, (_Float16)0.f, (_Float16)0.f,
                   (_Float16)0.f, (_Float16)0.f, (_Float16)0.f, (_Float16)0.f };
    for (int it = 0; it < NPP / 8; ++it) {       // 42 iters, pads have score 0
        const int p = it * 8 + sub;
        const float s = scores[p];
        const unsigned pp = tab[p];
        const int fi = pp & 0xff, fj = pp >> 8;
        const _Float16 sh = (_Float16)s;
        half8 sv = { sh, sh, sh, sh, sh, sh, sh, sh };
        half8 x = *(const half8*)(&emb[fi][dg * 8]) * *(const half8*)(&emb[fj][dg * 8]);
        acc8 += sv * x;                           // v_pk_fma_f16
    }
    // reduce over sub (lane bits 3..5), then dot proj, reduce over dg (bits 0..2)
    float av[8];
    #pragma unroll
    for (int i = 0; i < 8; ++i) av[i] = (float)acc8[i];
    #pragma unroll
    for (int off = 8; off <= 32; off <<= 1) {
        #pragma unroll
        for (int i = 0; i < 8; ++i) av[i] += __shfl_xor(av[i], off, 64);
    }
    float4 pa = *(const float4*)(proj + dg * 8);
    float4 pb = *(const float4*)(proj + dg * 8 + 4);
    float part = av[0] * pa.x + av[1] * pa.y + av[2] * pa.z + av[3] * pa.w
               + av[4] * pb.x + av[5] * pb.y + av[6] * pb.z + av[7] * pb.w;
    #pragma unroll
    for (int off = 1; off <= 4; off <<= 1) part += __shfl_xor(part, off, 64);

    if (lane == 0) out[r] = lin + part;
}

extern "C" void kernel_launch(void* const* d_in, const int* in_sizes, int n_in,
                              void* d_out, int out_size, void* d_ws, size_t ws_size,
                              hipStream_t stream) {
    const int*   sparse = (const int*)  d_in[0];
    const float* dense  = (const float*)d_in[1];
    const float* etab   = (const float*)d_in[2];
    const float* ltab   = (const float*)d_in[3];
    const float* wdense = (const float*)d_in[4];
    const float* bias   = (const float*)d_in[5];
    const float* W1     = (const float*)d_in[6];
    const float* b1     = (const float*)d_in[7];
    const float* w2     = (const float*)d_in[8];
    const float* proj   = (const float*)d_in[9];
    float* outp = (float*)d_out;

    _Float16*       w1t = (_Float16*)d_ws;                          // 8192 B
    unsigned short* tab = (unsigned short*)((char*)d_ws + 8192);    //  672 B

    const int B = in_sizes[0] / NF;

    prep_kernel<<<dim3(1), dim3(256), 0, stream>>>(W1, w1t, tab);
    afm_kernel<<<dim3((B + WPB - 1) / WPB), dim3(BLOCK), 0, stream>>>(
        sparse, dense, etab, ltab, wdense, bias, b1, w2, proj, w1t, tab, outp, B);
    (void)n_in; (void)out_size; (void)ws_size;
}